// Round 12
// baseline (256.742 us; speedup 1.0000x reference)
//
#include <hip/hip_runtime.h>
#include <math.h>

// Problem: S=4096, D=512, H=8, KVH=4, DH=64, M=64, K=8 (B=1)
// ARITHMETIC CONTRACT (frozen, round 5 green): selection-critical path
// emulates numpy-f32 op-for-op:
//  - QKV gemm: per output, sequential f32 fmaf chain in k-ascending order,
//    KC=384 panel split, final __fadd_rn(acc1, acc2)   [add in rope]
//  - k1/k2 sums: sequential f32 adds in axis order
//  - stage-1 scores: sequential fmaf chain over d (0..31)   [in GEMM, transposed store]
//  - stage-2 einsum: sequential f32 mul+add (NOT fma) over d (0..63)
//  - tables: correctly-rounded f32 (f64 then round)
//  - top-k: descending, ties -> lower index (bubble-insert == argmax-iter)
//  - softmax: *0.125, __expf (value-path), pairwise-8 sum, f32 div
// Round 11: stage-1 top-8 moved to lane-parallel VALU kernel (sel1) fed by
// transposed scores; attn_sel2 keeps stage-2 + ONE bitonic + epilogue.

// Workspace (floats)
static constexpr size_t OFF_P1   = 0;             // 4096*1024 panel1 / scoresT
static constexpr size_t OFF_P2   = 4194304;       // 4096*1024 panel2 / out partials
static constexpr size_t OFF_Q    = 8388608;       // 8*4096*64   q[h][s][d]
static constexpr size_t OFF_K    = 10485760;      // 4*4096*64   k[kvh][s][d]
static constexpr size_t OFF_V    = 11534336;      // 4*4096*64   v[kvh][s][d]
static constexpr size_t OFF_COS  = 12582912;      // 4096*32
static constexpr size_t OFF_SIN  = 12713984;      // 4096*32
static constexpr size_t OFF_K1   = 12845056;      // 4*64*32     k1[kvh][r][d]
static constexpr size_t OFF_K2   = 12853248;      // 4*64*32     k2[kvh][c][d]
static constexpr size_t OFF_O    = 12861440;      // 4096*512
static constexpr size_t OFF_W    = 14958592;      // 1024*512
static constexpr size_t OFF_PACK = 15482880;      // 32768*4 (ulonglong2 per query)

#define LDB 132   // 128-tile GEMM LDS leading-dim pad

__device__ __forceinline__ float rdlane_f(float v, int lane) {
  return __int_as_float(__builtin_amdgcn_readlane(__float_as_int(v), lane));
}

__global__ __launch_bounds__(256) void freq_table_kernel(float* __restrict__ cosT,
    float* __restrict__ sinT) {
  int idx = blockIdx.x * 256 + threadIdx.x;   // 0..131071
  int s = idx >> 5;
  int dp = idx & 31;
  double e = (double)dp * (1.0 / 32.0);
  float pf = (float)pow(10000.0, e);
  float invf = 1.0f / pf;
  float argf = __fmul_rn((float)s, invf);
  cosT[idx] = (float)cos((double)argf);
  sinT[idx] = (float)sin((double)argf);
}

// Panel NT gemm: 128x128 tile, 8x8/thread, single fmaf chain over
// k in [z?ksplit:0, z?512:ksplit), k-ascending. C_z gets the partial sum.
__global__ __launch_bounds__(256) void gemm128_panel(const float* __restrict__ A,
    const float* __restrict__ B, float* __restrict__ C1, float* __restrict__ C2,
    int N, int ksplit) {
  __shared__ float As[16 * LDB];
  __shared__ float Bs[16 * LDB];
  const int tid = threadIdx.x;
  const int z = blockIdx.z;
  const int k0 = z ? ksplit : 0;
  const int k1 = z ? 512 : ksplit;
  float* __restrict__ C = z ? C2 : C1;
  const int bm = blockIdx.y, bn = blockIdx.x;
  const int lrow = tid >> 1;          // 0..127
  const int lko = (tid & 1) << 3;     // 0 or 8
  const int ty = tid >> 4;            // 0..15
  const int tx = tid & 15;            // 0..15
  const float* Ap = A + (size_t)(bm * 128 + lrow) * 512 + lko;
  const float* Bp = B + (size_t)(bn * 128 + lrow) * 512 + lko;
  float acc[8][8] = {{0.f}};
  float4 a0 = *(const float4*)(Ap + k0);
  float4 a1 = *(const float4*)(Ap + k0 + 4);
  float4 b0 = *(const float4*)(Bp + k0);
  float4 b1 = *(const float4*)(Bp + k0 + 4);
  for (int kt = k0; kt < k1; kt += 16) {
    __syncthreads();
    As[(lko + 0) * LDB + lrow] = a0.x;
    As[(lko + 1) * LDB + lrow] = a0.y;
    As[(lko + 2) * LDB + lrow] = a0.z;
    As[(lko + 3) * LDB + lrow] = a0.w;
    As[(lko + 4) * LDB + lrow] = a1.x;
    As[(lko + 5) * LDB + lrow] = a1.y;
    As[(lko + 6) * LDB + lrow] = a1.z;
    As[(lko + 7) * LDB + lrow] = a1.w;
    Bs[(lko + 0) * LDB + lrow] = b0.x;
    Bs[(lko + 1) * LDB + lrow] = b0.y;
    Bs[(lko + 2) * LDB + lrow] = b0.z;
    Bs[(lko + 3) * LDB + lrow] = b0.w;
    Bs[(lko + 4) * LDB + lrow] = b1.x;
    Bs[(lko + 5) * LDB + lrow] = b1.y;
    Bs[(lko + 6) * LDB + lrow] = b1.z;
    Bs[(lko + 7) * LDB + lrow] = b1.w;
    __syncthreads();
    if (kt + 16 < k1) {               // prefetch next tile
      a0 = *(const float4*)(Ap + kt + 16);
      a1 = *(const float4*)(Ap + kt + 20);
      b0 = *(const float4*)(Bp + kt + 16);
      b1 = *(const float4*)(Bp + kt + 20);
    }
    #pragma unroll
    for (int k = 0; k < 16; ++k) {
      float4 al = *(const float4*)(&As[k * LDB + (ty << 2)]);
      float4 ah = *(const float4*)(&As[k * LDB + 64 + (ty << 2)]);
      float4 bl = *(const float4*)(&Bs[k * LDB + (tx << 2)]);
      float4 bh = *(const float4*)(&Bs[k * LDB + 64 + (tx << 2)]);
      float af[8] = {al.x, al.y, al.z, al.w, ah.x, ah.y, ah.z, ah.w};
      float bf[8] = {bl.x, bl.y, bl.z, bl.w, bh.x, bh.y, bh.z, bh.w};
      #pragma unroll
      for (int i2 = 0; i2 < 8; ++i2)
        #pragma unroll
        for (int j2 = 0; j2 < 8; ++j2)
          acc[i2][j2] = fmaf(af[i2], bf[j2], acc[i2][j2]);
    }
  }
  #pragma unroll
  for (int i2 = 0; i2 < 8; ++i2) {
    int row = bm * 128 + ((i2 < 4) ? (ty << 2) + i2 : 64 + (ty << 2) + i2 - 4);
    float* Cp = C + (size_t)row * N + bn * 128;
    *(float4*)(Cp + (tx << 2))      = make_float4(acc[i2][0], acc[i2][1], acc[i2][2], acc[i2][3]);
    *(float4*)(Cp + 64 + (tx << 2)) = make_float4(acc[i2][4], acc[i2][5], acc[i2][6], acc[i2][7]);
  }
}

// d_out = fl32(p1 + p2)   (value path)
__global__ __launch_bounds__(256) void combine_kernel(const float* __restrict__ p1,
    const float* __restrict__ p2, float* __restrict__ out) {
  int i = blockIdx.x * 256 + threadIdx.x;
  out[i] = __fadd_rn(p1[i], p2[i]);
}

// qkv = fl32(p1+p2) (the contract's panel add), then RoPE + reshape.
__global__ __launch_bounds__(256) void rope_reshape_kernel(const float* __restrict__ p1,
    const float* __restrict__ p2, const float* __restrict__ cosT,
    const float* __restrict__ sinT, float* __restrict__ qb,
    float* __restrict__ kb, float* __restrict__ vb) {
  int idx = blockIdx.x * 256 + threadIdx.x;
  int s = idx >> 10;
  int n = idx & 1023;
  float val = __fadd_rn(p1[idx], p2[idx]);
  int d = n & 63;
  if (n < 768) {
    int dp = d & 31;
    float cs = cosT[(s << 5) + dp];
    float sn = sinT[(s << 5) + dp];
    int npart = (n - d) + ((d < 32) ? d + 32 : d - 32);
    int pidx = (s << 10) + npart;
    float partner = __fadd_rn(p1[pidx], p2[pidx]);
    float rot = (d < 32) ? -partner : partner;
    float out = __fadd_rn(__fmul_rn(val, cs), __fmul_rn(rot, sn));
    if (n < 512) {
      int h = n >> 6;
      qb[((size_t)(h * 4096 + s) << 6) + d] = out;
    } else {
      int kvh = (n - 512) >> 6;
      kb[((size_t)(kvh * 4096 + s) << 6) + d] = out;
    }
  } else {
    int kvh = (n - 768) >> 6;
    vb[((size_t)(kvh * 4096 + s) << 6) + d] = val;
  }
}

__global__ __launch_bounds__(256) void k12_np_kernel(const float* __restrict__ kb,
    float* __restrict__ k1t, float* __restrict__ k2t) {
  int id = blockIdx.x * 256 + threadIdx.x;    // 0..16383
  int which = id >> 13;
  int rem = id & 8191;
  int kvh = rem >> 11;
  int rem2 = rem & 2047;
  int i = rem2 >> 5;
  int d = rem2 & 31;
  const float* base = kb + ((size_t)(kvh * 4096) << 6);
  if (which == 0) {
    float acc = base[((size_t)(i * 64) << 6) + d];
    for (int c = 1; c < 64; ++c)
      acc = __fadd_rn(acc, base[((size_t)(i * 64 + c) << 6) + d]);
    k1t[(kvh * 64 + i) * 32 + d] = acc;
  } else {
    float acc = base[((size_t)i << 6) + d + 32];
    for (int r = 1; r < 64; ++r)
      acc = __fadd_rn(acc, base[((size_t)(r * 64 + i) << 6) + d + 32]);
    k2t[(kvh * 64 + i) * 32 + d] = acc;
  }
}

// Stage-1 scores, TRANSPOSED store: scT[h][r][s], r<64 -> q[0:32]·k1[r],
// r>=64 -> q[32:64]·k2[r-64]. Per-output fmaf chain over dp ascending
// (identical rounding to previous layout; only the store address changes).
__global__ __launch_bounds__(256) void stage1_scoresT_kernel(
    const float* __restrict__ qb, const float* __restrict__ k1t,
    const float* __restrict__ k2t, float* __restrict__ scT) {
  __shared__ float qs[64 * 68];     // [d][s]
  __shared__ float kd[32 * 132];    // [dp][r2]
  const int t = threadIdx.x;
  const int h = blockIdx.y;
  const int s0 = blockIdx.x * 64;
  const int kvh = h >> 1;
  #pragma unroll
  for (int i = 0; i < 16; ++i) {
    int j = t + i * 256;
    int ss = j >> 6, d = j & 63;
    qs[d * 68 + ss] = qb[((size_t)(h * 4096 + s0 + ss) << 6) + d];
  }
  #pragma unroll
  for (int i = 0; i < 8; ++i) {
    int j = t + i * 256;
    int r = j >> 5, d = j & 31;
    kd[d * 132 + r]      = k1t[(kvh * 64 + r) * 32 + d];
    kd[d * 132 + 64 + r] = k2t[(kvh * 64 + r) * 32 + d];
  }
  __syncthreads();
  const int ty = t >> 4;            // r-group: rows ty*4..+3 in each half
  const int tx = t & 15;            // s-group: cols tx*4..+3
  float acc1[4][4] = {{0.f}};
  float acc2[4][4] = {{0.f}};
  #pragma unroll
  for (int dp = 0; dp < 32; ++dp) {
    float4 kv1 = *(const float4*)&kd[dp * 132 + (ty << 2)];
    float4 kv2 = *(const float4*)&kd[dp * 132 + 64 + (ty << 2)];
    float4 q1 = *(const float4*)&qs[dp * 68 + (tx << 2)];
    float4 q2 = *(const float4*)&qs[(32 + dp) * 68 + (tx << 2)];
    float k1f[4] = {kv1.x, kv1.y, kv1.z, kv1.w};
    float k2f[4] = {kv2.x, kv2.y, kv2.z, kv2.w};
    float q1f[4] = {q1.x, q1.y, q1.z, q1.w};
    float q2f[4] = {q2.x, q2.y, q2.z, q2.w};
    #pragma unroll
    for (int i2 = 0; i2 < 4; ++i2)
      #pragma unroll
      for (int j2 = 0; j2 < 4; ++j2) {
        acc1[i2][j2] = fmaf(k1f[i2], q1f[j2], acc1[i2][j2]);
        acc2[i2][j2] = fmaf(k2f[i2], q2f[j2], acc2[i2][j2]);
      }
  }
  float* base = scT + (size_t)h * 524288 + s0 + (tx << 2);
  #pragma unroll
  for (int i2 = 0; i2 < 4; ++i2) {
    *(float4*)(base + (size_t)((ty << 2) + i2) * 4096) =
        make_float4(acc1[i2][0], acc1[i2][1], acc1[i2][2], acc1[i2][3]);
    *(float4*)(base + (size_t)(64 + (ty << 2) + i2) * 4096) =
        make_float4(acc2[i2][0], acc2[i2][1], acc2[i2][2], acc2[i2][3]);
  }
}

// Lane-parallel stage-1 top-8: one lane per query; branchless 8-deep
// bubble-insert (strict > ; r ascending => stable => lower-index ties).
__global__ __launch_bounds__(64) void sel1_kernel(const float* __restrict__ scT,
    ulonglong2* __restrict__ packs) {
  const int w = blockIdx.x * 64 + threadIdx.x;
  const int h = w >> 12;
  const int s = w & 4095;
  const float* base = scT + (size_t)h * 524288 + s;
  unsigned long long pk[2];
  #pragma unroll
  for (int set = 0; set < 2; ++set) {
    const float* p = base + (size_t)set * 64 * 4096;
    float top[8];
    int idx[8];
    #pragma unroll
    for (int t = 0; t < 8; ++t) { top[t] = -INFINITY; idx[t] = 0; }
    #pragma unroll
    for (int r = 0; r < 64; ++r) {
      float v = p[(size_t)r * 4096];
      int i = r;
      #pragma unroll
      for (int j = 0; j < 8; ++j) {
        bool gt = v > top[j];
        float tv = top[j]; int ti = idx[j];
        top[j] = gt ? v : tv;
        idx[j] = gt ? i : ti;
        v = gt ? tv : v;
        i = gt ? ti : i;
      }
    }
    unsigned long long pp = 0;
    #pragma unroll
    for (int t = 0; t < 8; ++t) pp |= (unsigned long long)idx[t] << (6 * t);
    pk[set] = pp;
  }
  ulonglong2 out;
  out.x = pk[0];
  out.y = pk[1];
  packs[w] = out;
}

// Values-only bitonic sort (descending).
__device__ __forceinline__ void bitonic64_val_desc(float& v, int lane) {
  #pragma unroll
  for (int k = 2; k <= 64; k <<= 1) {
    #pragma unroll
    for (int j = k >> 1; j >= 1; j >>= 1) {
      float ov = __shfl_xor(v, j, 64);
      bool up = ((lane & k) == 0) == ((lane & j) == 0);
      float mx = fmaxf(v, ov), mn = fminf(v, ov);
      v = up ? mx : mn;
    }
  }
}

// Stage-2 + epilogue: one wave per query. Reads packed stage-1 indices.
__global__ __launch_bounds__(256) void attn_sel2_kernel(
    const ulonglong2* __restrict__ packs, const float* __restrict__ qb,
    const float* __restrict__ vb, const float* __restrict__ k1t,
    const float* __restrict__ k2t, float* __restrict__ ob) {
  const int lane = threadIdx.x & 63;
  const int w = blockIdx.x * 4 + (threadIdx.x >> 6);   // w = h*4096 + s
  const int h = w >> 12;
  const int s = w & 4095;
  const int kvh = h >> 1;
  ulonglong2 pk = packs[w];          // uniform address -> broadcast
  const unsigned long long pack1 = pk.x, pack2 = pk.y;
  const float qv = qb[((size_t)w << 6) + lane];

  // stage-2: lane c = it1*8+it2; mul+add chain over d=0..63 (non-fma)
  int r1 = (int)((pack1 >> (6 * (lane >> 3))) & 63);
  int r2 = (int)((pack2 >> (6 * (lane & 7))) & 63);
  const float* k1p = k1t + (size_t)(kvh * 64 + r1) * 32;
  const float* k2p = k2t + (size_t)(kvh * 64 + r2) * 32;
  float c = 0.f;
  #pragma unroll
  for (int dq = 0; dq < 32; dq += 4) {
    float4 kk = *(const float4*)(k1p + dq);
    c = __fadd_rn(c, __fmul_rn(rdlane_f(qv, dq + 0), kk.x));
    c = __fadd_rn(c, __fmul_rn(rdlane_f(qv, dq + 1), kk.y));
    c = __fadd_rn(c, __fmul_rn(rdlane_f(qv, dq + 2), kk.z));
    c = __fadd_rn(c, __fmul_rn(rdlane_f(qv, dq + 3), kk.w));
  }
  #pragma unroll
  for (int dq = 0; dq < 32; dq += 4) {
    float4 kk = *(const float4*)(k2p + dq);
    c = __fadd_rn(c, __fmul_rn(rdlane_f(qv, 32 + dq + 0), kk.x));
    c = __fadd_rn(c, __fmul_rn(rdlane_f(qv, 32 + dq + 1), kk.y));
    c = __fadd_rn(c, __fmul_rn(rdlane_f(qv, 32 + dq + 2), kk.z));
    c = __fadd_rn(c, __fmul_rn(rdlane_f(qv, 32 + dq + 3), kk.w));
  }
  const float scand = c;
  float v3 = c;
  bitonic64_val_desc(v3, lane);
  float cvs[8]; int ccs[8];
  unsigned long long used = 0;
  #pragma unroll
  for (int t = 0; t < 8; ++t) {
    float tv = rdlane_f(v3, t);
    unsigned long long m = __ballot(scand == tv) & ~used;
    int ix = __ffsll((long long)m) - 1;
    used |= 1ull << ix;
    cvs[t] = tv;
    ccs[t] = ix;
  }
  float y[8];
  #pragma unroll
  for (int t = 0; t < 8; ++t) y[t] = cvs[t] * 0.125f;
  float mx = y[0];
  #pragma unroll
  for (int t = 1; t < 8; ++t) if (y[t] > mx) mx = y[t];
  float e[8];
  #pragma unroll
  for (int t = 0; t < 8; ++t) e[t] = __expf(__fsub_rn(y[t], mx));
  float wsum = __fadd_rn(__fadd_rn(__fadd_rn(e[0], e[1]), __fadd_rn(e[2], e[3])),
                         __fadd_rn(__fadd_rn(e[4], e[5]), __fadd_rn(e[6], e[7])));
  const float* vbh = vb + ((size_t)kvh << 18);
  float o = 0.f;
  #pragma unroll
  for (int t = 0; t < 8; ++t) {
    float att = __fdiv_rn(e[t], wsum);
    int row = (int)((pack1 >> (6 * (ccs[t] >> 3))) & 63);
    int col = (int)((pack2 >> (6 * (ccs[t] & 7))) & 63);
    o = __fadd_rn(o, __fmul_rn(att, vbh[((size_t)(row * 64 + col) << 6) + lane]));
  }
  ob[(size_t)s * 512 + (h << 6) + lane] = o;
}

extern "C" void kernel_launch(void* const* d_in, const int* in_sizes, int n_in,
                              void* d_out, int out_size, void* d_ws, size_t ws_size,
                              hipStream_t stream) {
  const float* x  = (const float*)d_in[0];
  const float* Wq = (const float*)d_in[1];
  const float* Wk = (const float*)d_in[2];
  const float* Wv = (const float*)d_in[3];
  const float* Wo = (const float*)d_in[4];
  float* ws = (float*)d_ws;
  float* p1   = ws + OFF_P1;
  float* p2   = ws + OFF_P2;
  float* qb   = ws + OFF_Q;
  float* kb   = ws + OFF_K;
  float* vb   = ws + OFF_V;
  float* cosT = ws + OFF_COS;
  float* sinT = ws + OFF_SIN;
  float* k1t  = ws + OFF_K1;
  float* k2t  = ws + OFF_K2;
  float* ob   = ws + OFF_O;
  float* wcat = ws + OFF_W;
  float* scT  = ws + OFF_P1;          // scoresT reuse panel1 buffer
  float* op1  = ws + OFF_P2;          // out partials reuse panel2 buffer
  float* op2  = ws + OFF_P2 + 2097152;
  ulonglong2* packs = (ulonglong2*)(ws + OFF_PACK);

  hipMemcpyAsync(wcat,             Wq, (size_t)512 * 512 * sizeof(float), hipMemcpyDeviceToDevice, stream);
  hipMemcpyAsync(wcat + 512 * 512, Wk, (size_t)256 * 512 * sizeof(float), hipMemcpyDeviceToDevice, stream);
  hipMemcpyAsync(wcat + 768 * 512, Wv, (size_t)256 * 512 * sizeof(float), hipMemcpyDeviceToDevice, stream);

  freq_table_kernel<<<512, 256, 0, stream>>>(cosT, sinT);
  // QKV: selection-critical KC=384 panel split via grid-z
  gemm128_panel<<<dim3(8, 32, 2), 256, 0, stream>>>(x, wcat, p1, p2, 1024, 384);
  rope_reshape_kernel<<<16384, 256, 0, stream>>>(p1, p2, cosT, sinT, qb, kb, vb);
  k12_np_kernel<<<64, 256, 0, stream>>>(kb, k1t, k2t);
  stage1_scoresT_kernel<<<dim3(64, 8), 256, 0, stream>>>(qb, k1t, k2t, scT);
  sel1_kernel<<<512, 64, 0, stream>>>(scT, packs);
  attn_sel2_kernel<<<8192, 256, 0, stream>>>(packs, qb, vb, k1t, k2t, ob);
  // Output projection: value-path, split-k at 256 via grid-z + combine
  gemm128_panel<<<dim3(4, 32, 2), 256, 0, stream>>>(ob, Wo, op1, op2, 512, 256);
  combine_kernel<<<8192, 256, 0, stream>>>(op1, op2, (float*)d_out);
}

// Round 13
// 241.647 us; speedup vs baseline: 1.0625x; 1.0625x over previous
//
#include <hip/hip_runtime.h>
#include <math.h>

// Problem: S=4096, D=512, H=8, KVH=4, DH=64, M=64, K=8 (B=1)
// ARITHMETIC CONTRACT (frozen, round 5 green): selection-critical path
// emulates numpy-f32 op-for-op:
//  - QKV gemm: per output, sequential f32 fmaf chain in k-ascending order,
//    KC=384 panel split, final __fadd_rn(acc1, acc2)   [add in rope]
//  - k1/k2 sums: sequential f32 adds in axis order
//  - stage-1 scores: sequential fmaf chain over dp (0..31)  [in fused kernel]
//  - stage-2 einsum: sequential f32 mul+add (NOT fma) over d (0..63)
//  - tables: correctly-rounded f32 (f64 then round)
//  - top-k: descending, ties -> lower index (bubble-insert == argmax-iter)
//  - softmax: *0.125, __expf (value-path), pairwise-8 sum, f32 div
// Round 13: stage-1 scores + selection FUSED in one kernel (LDS tile, no HBM
// round-trip); QKV gemm reads Wq/Wk/Wv directly (no concat memcpys).

// Workspace (floats)
static constexpr size_t OFF_P1   = 0;             // 4096*1024 panel1
static constexpr size_t OFF_P2   = 4194304;       // 4096*1024 panel2 / out partials
static constexpr size_t OFF_Q    = 8388608;       // 8*4096*64   q[h][s][d]
static constexpr size_t OFF_K    = 10485760;      // 4*4096*64   k[kvh][s][d]
static constexpr size_t OFF_V    = 11534336;      // 4*4096*64   v[kvh][s][d]
static constexpr size_t OFF_COS  = 12582912;      // 4096*32
static constexpr size_t OFF_SIN  = 12713984;      // 4096*32
static constexpr size_t OFF_K1   = 12845056;      // 4*64*32     k1[kvh][r][d]
static constexpr size_t OFF_K2   = 12853248;      // 4*64*32     k2[kvh][c][d]
static constexpr size_t OFF_O    = 12861440;      // 4096*512
static constexpr size_t OFF_PACK = 14958592;      // 32768*4 (ulonglong2 per query)

#define LDB 132   // 128-tile GEMM LDS leading-dim pad

__device__ __forceinline__ float rdlane_f(float v, int lane) {
  return __int_as_float(__builtin_amdgcn_readlane(__float_as_int(v), lane));
}

__global__ __launch_bounds__(256) void freq_table_kernel(float* __restrict__ cosT,
    float* __restrict__ sinT) {
  int idx = blockIdx.x * 256 + threadIdx.x;   // 0..131071
  int s = idx >> 5;
  int dp = idx & 31;
  double e = (double)dp * (1.0 / 32.0);
  float pf = (float)pow(10000.0, e);
  float invf = 1.0f / pf;
  float argf = __fmul_rn((float)s, invf);
  cosT[idx] = (float)cos((double)argf);
  sinT[idx] = (float)sin((double)argf);
}

// QKV panel NT gemm reading Wq/Wk/Wv directly (block-uniform select by bn).
// 128x128 tile, 8x8/thread, fmaf chain over k in panel range, k-ascending.
__global__ __launch_bounds__(256) void gemm128_qkv(const float* __restrict__ A,
    const float* __restrict__ Wq, const float* __restrict__ Wk,
    const float* __restrict__ Wv, float* __restrict__ C1,
    float* __restrict__ C2) {
  __shared__ float As[16 * LDB];
  __shared__ float Bs[16 * LDB];
  const int tid = threadIdx.x;
  const int z = blockIdx.z;
  const int k0 = z ? 384 : 0;
  const int k1 = z ? 512 : 384;
  float* __restrict__ C = z ? C2 : C1;
  const int bm = blockIdx.y, bn = blockIdx.x;
  const int lrow = tid >> 1;          // 0..127
  const int lko = (tid & 1) << 3;     // 0 or 8
  const int ty = tid >> 4;
  const int tx = tid & 15;
  const float* Bbase = (bn < 4) ? (Wq + ((size_t)bn * 128) * 512)
                     : (bn < 6) ? (Wk + ((size_t)(bn - 4) * 128) * 512)
                                : (Wv + ((size_t)(bn - 6) * 128) * 512);
  const float* Ap = A + (size_t)(bm * 128 + lrow) * 512 + lko;
  const float* Bp = Bbase + (size_t)lrow * 512 + lko;
  float acc[8][8] = {{0.f}};
  float4 a0 = *(const float4*)(Ap + k0);
  float4 a1 = *(const float4*)(Ap + k0 + 4);
  float4 b0 = *(const float4*)(Bp + k0);
  float4 b1 = *(const float4*)(Bp + k0 + 4);
  for (int kt = k0; kt < k1; kt += 16) {
    __syncthreads();
    As[(lko + 0) * LDB + lrow] = a0.x;
    As[(lko + 1) * LDB + lrow] = a0.y;
    As[(lko + 2) * LDB + lrow] = a0.z;
    As[(lko + 3) * LDB + lrow] = a0.w;
    As[(lko + 4) * LDB + lrow] = a1.x;
    As[(lko + 5) * LDB + lrow] = a1.y;
    As[(lko + 6) * LDB + lrow] = a1.z;
    As[(lko + 7) * LDB + lrow] = a1.w;
    Bs[(lko + 0) * LDB + lrow] = b0.x;
    Bs[(lko + 1) * LDB + lrow] = b0.y;
    Bs[(lko + 2) * LDB + lrow] = b0.z;
    Bs[(lko + 3) * LDB + lrow] = b0.w;
    Bs[(lko + 4) * LDB + lrow] = b1.x;
    Bs[(lko + 5) * LDB + lrow] = b1.y;
    Bs[(lko + 6) * LDB + lrow] = b1.z;
    Bs[(lko + 7) * LDB + lrow] = b1.w;
    __syncthreads();
    if (kt + 16 < k1) {
      a0 = *(const float4*)(Ap + kt + 16);
      a1 = *(const float4*)(Ap + kt + 20);
      b0 = *(const float4*)(Bp + kt + 16);
      b1 = *(const float4*)(Bp + kt + 20);
    }
    #pragma unroll
    for (int k = 0; k < 16; ++k) {
      float4 al = *(const float4*)(&As[k * LDB + (ty << 2)]);
      float4 ah = *(const float4*)(&As[k * LDB + 64 + (ty << 2)]);
      float4 bl = *(const float4*)(&Bs[k * LDB + (tx << 2)]);
      float4 bh = *(const float4*)(&Bs[k * LDB + 64 + (tx << 2)]);
      float af[8] = {al.x, al.y, al.z, al.w, ah.x, ah.y, ah.z, ah.w};
      float bf[8] = {bl.x, bl.y, bl.z, bl.w, bh.x, bh.y, bh.z, bh.w};
      #pragma unroll
      for (int i2 = 0; i2 < 8; ++i2)
        #pragma unroll
        for (int j2 = 0; j2 < 8; ++j2)
          acc[i2][j2] = fmaf(af[i2], bf[j2], acc[i2][j2]);
    }
  }
  #pragma unroll
  for (int i2 = 0; i2 < 8; ++i2) {
    int row = bm * 128 + ((i2 < 4) ? (ty << 2) + i2 : 64 + (ty << 2) + i2 - 4);
    float* Cp = C + (size_t)row * 1024 + bn * 128;
    *(float4*)(Cp + (tx << 2))      = make_float4(acc[i2][0], acc[i2][1], acc[i2][2], acc[i2][3]);
    *(float4*)(Cp + 64 + (tx << 2)) = make_float4(acc[i2][4], acc[i2][5], acc[i2][6], acc[i2][7]);
  }
}

// Generic panel NT gemm (for the output projection, value path).
__global__ __launch_bounds__(256) void gemm128_panel(const float* __restrict__ A,
    const float* __restrict__ B, float* __restrict__ C1, float* __restrict__ C2,
    int N, int ksplit) {
  __shared__ float As[16 * LDB];
  __shared__ float Bs[16 * LDB];
  const int tid = threadIdx.x;
  const int z = blockIdx.z;
  const int k0 = z ? ksplit : 0;
  const int k1 = z ? 512 : ksplit;
  float* __restrict__ C = z ? C2 : C1;
  const int bm = blockIdx.y, bn = blockIdx.x;
  const int lrow = tid >> 1;
  const int lko = (tid & 1) << 3;
  const int ty = tid >> 4;
  const int tx = tid & 15;
  const float* Ap = A + (size_t)(bm * 128 + lrow) * 512 + lko;
  const float* Bp = B + (size_t)(bn * 128 + lrow) * 512 + lko;
  float acc[8][8] = {{0.f}};
  float4 a0 = *(const float4*)(Ap + k0);
  float4 a1 = *(const float4*)(Ap + k0 + 4);
  float4 b0 = *(const float4*)(Bp + k0);
  float4 b1 = *(const float4*)(Bp + k0 + 4);
  for (int kt = k0; kt < k1; kt += 16) {
    __syncthreads();
    As[(lko + 0) * LDB + lrow] = a0.x;
    As[(lko + 1) * LDB + lrow] = a0.y;
    As[(lko + 2) * LDB + lrow] = a0.z;
    As[(lko + 3) * LDB + lrow] = a0.w;
    As[(lko + 4) * LDB + lrow] = a1.x;
    As[(lko + 5) * LDB + lrow] = a1.y;
    As[(lko + 6) * LDB + lrow] = a1.z;
    As[(lko + 7) * LDB + lrow] = a1.w;
    Bs[(lko + 0) * LDB + lrow] = b0.x;
    Bs[(lko + 1) * LDB + lrow] = b0.y;
    Bs[(lko + 2) * LDB + lrow] = b0.z;
    Bs[(lko + 3) * LDB + lrow] = b0.w;
    Bs[(lko + 4) * LDB + lrow] = b1.x;
    Bs[(lko + 5) * LDB + lrow] = b1.y;
    Bs[(lko + 6) * LDB + lrow] = b1.z;
    Bs[(lko + 7) * LDB + lrow] = b1.w;
    __syncthreads();
    if (kt + 16 < k1) {
      a0 = *(const float4*)(Ap + kt + 16);
      a1 = *(const float4*)(Ap + kt + 20);
      b0 = *(const float4*)(Bp + kt + 16);
      b1 = *(const float4*)(Bp + kt + 20);
    }
    #pragma unroll
    for (int k = 0; k < 16; ++k) {
      float4 al = *(const float4*)(&As[k * LDB + (ty << 2)]);
      float4 ah = *(const float4*)(&As[k * LDB + 64 + (ty << 2)]);
      float4 bl = *(const float4*)(&Bs[k * LDB + (tx << 2)]);
      float4 bh = *(const float4*)(&Bs[k * LDB + 64 + (tx << 2)]);
      float af[8] = {al.x, al.y, al.z, al.w, ah.x, ah.y, ah.z, ah.w};
      float bf[8] = {bl.x, bl.y, bl.z, bl.w, bh.x, bh.y, bh.z, bh.w};
      #pragma unroll
      for (int i2 = 0; i2 < 8; ++i2)
        #pragma unroll
        for (int j2 = 0; j2 < 8; ++j2)
          acc[i2][j2] = fmaf(af[i2], bf[j2], acc[i2][j2]);
    }
  }
  #pragma unroll
  for (int i2 = 0; i2 < 8; ++i2) {
    int row = bm * 128 + ((i2 < 4) ? (ty << 2) + i2 : 64 + (ty << 2) + i2 - 4);
    float* Cp = C + (size_t)row * N + bn * 128;
    *(float4*)(Cp + (tx << 2))      = make_float4(acc[i2][0], acc[i2][1], acc[i2][2], acc[i2][3]);
    *(float4*)(Cp + 64 + (tx << 2)) = make_float4(acc[i2][4], acc[i2][5], acc[i2][6], acc[i2][7]);
  }
}

// d_out = fl32(p1 + p2)   (value path)
__global__ __launch_bounds__(256) void combine_kernel(const float* __restrict__ p1,
    const float* __restrict__ p2, float* __restrict__ out) {
  int i = blockIdx.x * 256 + threadIdx.x;
  out[i] = __fadd_rn(p1[i], p2[i]);
}

// qkv = fl32(p1+p2) (the contract's panel add), then RoPE + reshape.
__global__ __launch_bounds__(256) void rope_reshape_kernel(const float* __restrict__ p1,
    const float* __restrict__ p2, const float* __restrict__ cosT,
    const float* __restrict__ sinT, float* __restrict__ qb,
    float* __restrict__ kb, float* __restrict__ vb) {
  int idx = blockIdx.x * 256 + threadIdx.x;
  int s = idx >> 10;
  int n = idx & 1023;
  float val = __fadd_rn(p1[idx], p2[idx]);
  int d = n & 63;
  if (n < 768) {
    int dp = d & 31;
    float cs = cosT[(s << 5) + dp];
    float sn = sinT[(s << 5) + dp];
    int npart = (n - d) + ((d < 32) ? d + 32 : d - 32);
    int pidx = (s << 10) + npart;
    float partner = __fadd_rn(p1[pidx], p2[pidx]);
    float rot = (d < 32) ? -partner : partner;
    float out = __fadd_rn(__fmul_rn(val, cs), __fmul_rn(rot, sn));
    if (n < 512) {
      int h = n >> 6;
      qb[((size_t)(h * 4096 + s) << 6) + d] = out;
    } else {
      int kvh = (n - 512) >> 6;
      kb[((size_t)(kvh * 4096 + s) << 6) + d] = out;
    }
  } else {
    int kvh = (n - 768) >> 6;
    vb[((size_t)(kvh * 4096 + s) << 6) + d] = val;
  }
}

__global__ __launch_bounds__(256) void k12_np_kernel(const float* __restrict__ kb,
    float* __restrict__ k1t, float* __restrict__ k2t) {
  int id = blockIdx.x * 256 + threadIdx.x;    // 0..16383
  int which = id >> 13;
  int rem = id & 8191;
  int kvh = rem >> 11;
  int rem2 = rem & 2047;
  int i = rem2 >> 5;
  int d = rem2 & 31;
  const float* base = kb + ((size_t)(kvh * 4096) << 6);
  if (which == 0) {
    float acc = base[((size_t)(i * 64) << 6) + d];
    for (int c = 1; c < 64; ++c)
      acc = __fadd_rn(acc, base[((size_t)(i * 64 + c) << 6) + d]);
    k1t[(kvh * 64 + i) * 32 + d] = acc;
  } else {
    float acc = base[((size_t)i << 6) + d + 32];
    for (int r = 1; r < 64; ++r)
      acc = __fadd_rn(acc, base[((size_t)(r * 64 + i) << 6) + d + 32]);
    k2t[(kvh * 64 + i) * 32 + d] = acc;
  }
}

// FUSED stage-1: compute 128x64 score tile (same fmaf chains over dp
// ascending) into LDS, then 128 threads bubble-scan columns -> packed top-8.
// Bubble-insert with strict '>' over r ascending == iterative argmax with
// lower-index tie-break (lax.top_k semantics).
__global__ __launch_bounds__(256) void stage1_sel_kernel(
    const float* __restrict__ qb, const float* __restrict__ k1t,
    const float* __restrict__ k2t, unsigned long long* __restrict__ packs) {
  __shared__ float smem[8704];        // phase1: qs[0..4351], kd[4352..8575]
                                      // phase2: score tile [128][68]
  float* qs = smem;                   // [d][s] stride 68
  float* kd = smem + 4352;            // [dp][r2] stride 132
  const int t = threadIdx.x;
  const int h = blockIdx.y;
  const int s0 = blockIdx.x * 64;
  const int kvh = h >> 1;
  #pragma unroll
  for (int i = 0; i < 16; ++i) {
    int j = t + i * 256;
    int ss = j >> 6, d = j & 63;
    qs[d * 68 + ss] = qb[((size_t)(h * 4096 + s0 + ss) << 6) + d];
  }
  #pragma unroll
  for (int i = 0; i < 8; ++i) {
    int j = t + i * 256;
    int r = j >> 5, d = j & 31;
    kd[d * 132 + r]      = k1t[(kvh * 64 + r) * 32 + d];
    kd[d * 132 + 64 + r] = k2t[(kvh * 64 + r) * 32 + d];
  }
  __syncthreads();
  const int ty = t >> 4;              // r-group
  const int tx = t & 15;              // s-group
  float acc1[4][4] = {{0.f}};
  float acc2[4][4] = {{0.f}};
  #pragma unroll
  for (int dp = 0; dp < 32; ++dp) {
    float4 kv1 = *(const float4*)&kd[dp * 132 + (ty << 2)];
    float4 kv2 = *(const float4*)&kd[dp * 132 + 64 + (ty << 2)];
    float4 q1 = *(const float4*)&qs[dp * 68 + (tx << 2)];
    float4 q2 = *(const float4*)&qs[(32 + dp) * 68 + (tx << 2)];
    float k1f[4] = {kv1.x, kv1.y, kv1.z, kv1.w};
    float k2f[4] = {kv2.x, kv2.y, kv2.z, kv2.w};
    float q1f[4] = {q1.x, q1.y, q1.z, q1.w};
    float q2f[4] = {q2.x, q2.y, q2.z, q2.w};
    #pragma unroll
    for (int i2 = 0; i2 < 4; ++i2)
      #pragma unroll
      for (int j2 = 0; j2 < 4; ++j2) {
        acc1[i2][j2] = fmaf(k1f[i2], q1f[j2], acc1[i2][j2]);
        acc2[i2][j2] = fmaf(k2f[i2], q2f[j2], acc2[i2][j2]);
      }
  }
  __syncthreads();                    // all qs/kd reads done
  float* sct = smem;                  // [r2][s] stride 68 (aligned for b128)
  #pragma unroll
  for (int i2 = 0; i2 < 4; ++i2) {
    int r = (ty << 2) + i2;
    *(float4*)&sct[(size_t)r * 68 + (tx << 2)] =
        make_float4(acc1[i2][0], acc1[i2][1], acc1[i2][2], acc1[i2][3]);
    *(float4*)&sct[(size_t)(64 + r) * 68 + (tx << 2)] =
        make_float4(acc2[i2][0], acc2[i2][1], acc2[i2][2], acc2[i2][3]);
  }
  __syncthreads();
  if (t < 128) {
    int set = t >> 6;                 // 0: k1 scores, 1: k2 scores
    int sq = t & 63;                  // query within tile
    const float* p = sct + (size_t)(set << 6) * 68 + sq;
    float top[8];
    int idx[8];
    #pragma unroll
    for (int u = 0; u < 8; ++u) { top[u] = -INFINITY; idx[u] = 0; }
    #pragma unroll
    for (int r = 0; r < 64; ++r) {
      float v = p[(size_t)r * 68];
      int i = r;
      #pragma unroll
      for (int j = 0; j < 8; ++j) {
        bool gt = v > top[j];
        float tv = top[j]; int ti = idx[j];
        top[j] = gt ? v : tv;
        idx[j] = gt ? i : ti;
        v = gt ? tv : v;
        i = gt ? ti : i;
      }
    }
    unsigned long long pp = 0;
    #pragma unroll
    for (int u = 0; u < 8; ++u) pp |= (unsigned long long)idx[u] << (6 * u);
    packs[(((size_t)(h * 4096 + s0 + sq)) << 1) + set] = pp;
  }
}

// Values-only bitonic sort (descending).
__device__ __forceinline__ void bitonic64_val_desc(float& v, int lane) {
  #pragma unroll
  for (int k = 2; k <= 64; k <<= 1) {
    #pragma unroll
    for (int j = k >> 1; j >= 1; j >>= 1) {
      float ov = __shfl_xor(v, j, 64);
      bool up = ((lane & k) == 0) == ((lane & j) == 0);
      float mx = fmaxf(v, ov), mn = fminf(v, ov);
      v = up ? mx : mn;
    }
  }
}

// Stage-2 + epilogue: one wave per query. Reads packed stage-1 indices.
__global__ __launch_bounds__(256) void attn_sel2_kernel(
    const ulonglong2* __restrict__ packs, const float* __restrict__ qb,
    const float* __restrict__ vb, const float* __restrict__ k1t,
    const float* __restrict__ k2t, float* __restrict__ ob) {
  const int lane = threadIdx.x & 63;
  const int w = blockIdx.x * 4 + (threadIdx.x >> 6);   // w = h*4096 + s
  const int h = w >> 12;
  const int s = w & 4095;
  const int kvh = h >> 1;
  ulonglong2 pk = packs[w];
  const unsigned long long pack1 = pk.x, pack2 = pk.y;
  const float qv = qb[((size_t)w << 6) + lane];

  int r1 = (int)((pack1 >> (6 * (lane >> 3))) & 63);
  int r2 = (int)((pack2 >> (6 * (lane & 7))) & 63);
  const float* k1p = k1t + (size_t)(kvh * 64 + r1) * 32;
  const float* k2p = k2t + (size_t)(kvh * 64 + r2) * 32;
  float c = 0.f;
  #pragma unroll
  for (int dq = 0; dq < 32; dq += 4) {
    float4 kk = *(const float4*)(k1p + dq);
    c = __fadd_rn(c, __fmul_rn(rdlane_f(qv, dq + 0), kk.x));
    c = __fadd_rn(c, __fmul_rn(rdlane_f(qv, dq + 1), kk.y));
    c = __fadd_rn(c, __fmul_rn(rdlane_f(qv, dq + 2), kk.z));
    c = __fadd_rn(c, __fmul_rn(rdlane_f(qv, dq + 3), kk.w));
  }
  #pragma unroll
  for (int dq = 0; dq < 32; dq += 4) {
    float4 kk = *(const float4*)(k2p + dq);
    c = __fadd_rn(c, __fmul_rn(rdlane_f(qv, 32 + dq + 0), kk.x));
    c = __fadd_rn(c, __fmul_rn(rdlane_f(qv, 32 + dq + 1), kk.y));
    c = __fadd_rn(c, __fmul_rn(rdlane_f(qv, 32 + dq + 2), kk.z));
    c = __fadd_rn(c, __fmul_rn(rdlane_f(qv, 32 + dq + 3), kk.w));
  }
  const float scand = c;
  float v3 = c;
  bitonic64_val_desc(v3, lane);
  float cvs[8]; int ccs[8];
  unsigned long long used = 0;
  #pragma unroll
  for (int t = 0; t < 8; ++t) {
    float tv = rdlane_f(v3, t);
    unsigned long long m = __ballot(scand == tv) & ~used;
    int ix = __ffsll((long long)m) - 1;
    used |= 1ull << ix;
    cvs[t] = tv;
    ccs[t] = ix;
  }
  float y[8];
  #pragma unroll
  for (int t = 0; t < 8; ++t) y[t] = cvs[t] * 0.125f;
  float mx = y[0];
  #pragma unroll
  for (int t = 1; t < 8; ++t) if (y[t] > mx) mx = y[t];
  float e[8];
  #pragma unroll
  for (int t = 0; t < 8; ++t) e[t] = __expf(__fsub_rn(y[t], mx));
  float wsum = __fadd_rn(__fadd_rn(__fadd_rn(e[0], e[1]), __fadd_rn(e[2], e[3])),
                         __fadd_rn(__fadd_rn(e[4], e[5]), __fadd_rn(e[6], e[7])));
  const float* vbh = vb + ((size_t)kvh << 18);
  float o = 0.f;
  #pragma unroll
  for (int t = 0; t < 8; ++t) {
    float att = __fdiv_rn(e[t], wsum);
    int row = (int)((pack1 >> (6 * (ccs[t] >> 3))) & 63);
    int col = (int)((pack2 >> (6 * (ccs[t] & 7))) & 63);
    o = __fadd_rn(o, __fmul_rn(att, vbh[((size_t)(row * 64 + col) << 6) + lane]));
  }
  ob[(size_t)s * 512 + (h << 6) + lane] = o;
}

extern "C" void kernel_launch(void* const* d_in, const int* in_sizes, int n_in,
                              void* d_out, int out_size, void* d_ws, size_t ws_size,
                              hipStream_t stream) {
  const float* x  = (const float*)d_in[0];
  const float* Wq = (const float*)d_in[1];
  const float* Wk = (const float*)d_in[2];
  const float* Wv = (const float*)d_in[3];
  const float* Wo = (const float*)d_in[4];
  float* ws = (float*)d_ws;
  float* p1   = ws + OFF_P1;
  float* p2   = ws + OFF_P2;
  float* qb   = ws + OFF_Q;
  float* kb   = ws + OFF_K;
  float* vb   = ws + OFF_V;
  float* cosT = ws + OFF_COS;
  float* sinT = ws + OFF_SIN;
  float* k1t  = ws + OFF_K1;
  float* k2t  = ws + OFF_K2;
  float* ob   = ws + OFF_O;
  float* op1  = ws + OFF_P2;          // out partials reuse panel2 buffer
  float* op2  = ws + OFF_P2 + 2097152;
  unsigned long long* packs = (unsigned long long*)(ws + OFF_PACK);

  freq_table_kernel<<<512, 256, 0, stream>>>(cosT, sinT);
  // QKV: selection-critical KC=384 panel split via grid-z, direct W reads
  gemm128_qkv<<<dim3(8, 32, 2), 256, 0, stream>>>(x, Wq, Wk, Wv, p1, p2);
  rope_reshape_kernel<<<16384, 256, 0, stream>>>(p1, p2, cosT, sinT, qb, kb, vb);
  k12_np_kernel<<<64, 256, 0, stream>>>(kb, k1t, k2t);
  stage1_sel_kernel<<<dim3(64, 8), 256, 0, stream>>>(qb, k1t, k2t, packs);
  attn_sel2_kernel<<<8192, 256, 0, stream>>>((const ulonglong2*)packs, qb, vb, k1t, k2t, ob);
  // Output projection: value-path, split-k at 256 via grid-z + combine
  gemm128_panel<<<dim3(4, 32, 2), 256, 0, stream>>>(ob, Wo, op1, op2, 512, 256);
  combine_kernel<<<8192, 256, 0, stream>>>(op1, op2, (float*)d_out);
}

// Round 14
// 234.700 us; speedup vs baseline: 1.0939x; 1.0296x over previous
//
#include <hip/hip_runtime.h>
#include <math.h>

// Problem: S=4096, D=512, H=8, KVH=4, DH=64, M=64, K=8 (B=1)
// ARITHMETIC CONTRACT (frozen, round 5 green): selection-critical path
// emulates numpy-f32 op-for-op:
//  - QKV gemm: per output, sequential f32 fmaf chain in k-ascending order,
//    KC=384 panel split, final __fadd_rn(p1, p2)  [add at consumers]
//  - rope: val=fl32(p1+p2); out=fl32(fl32(val*cs)+fl32(rot*sn))  [on load]
//  - k1/k2 sums: sequential f32 adds in axis order
//  - stage-1 scores: sequential fmaf chain over dp (0..31)
//  - stage-2 einsum: sequential f32 mul+add (NOT fma) over d (0..63)
//  - tables: correctly-rounded f32 (f64 then round)
//  - top-k: descending, ties -> lower index (bubble-insert == argmax-iter)
//  - softmax: *0.125, __expf (value-path), pairwise-8 sum, f32 div
// Round 14: q/k never materialized (rope-on-load in consumers); QKV gemm
// LDS double-buffered (1 barrier/ktile); out-gemm 4-way split-k (2 blk/CU).

// Workspace (floats)
static constexpr size_t OFF_P1   = 0;             // 4096*1024 panel1 / out partials 0,1
static constexpr size_t OFF_P2   = 4194304;       // 4096*1024 panel2 / out partials 2,3
static constexpr size_t OFF_KB   = 8388608;       // 4*4096*64   roped k[kvh][s][d]
static constexpr size_t OFF_V    = 9437184;       // 4*4096*64   v[kvh][s][d]
static constexpr size_t OFF_COS  = 10485760;      // 4096*32
static constexpr size_t OFF_SIN  = 10616832;      // 4096*32
static constexpr size_t OFF_K1   = 10747904;      // 4*64*32     k1[kvh][r][d]
static constexpr size_t OFF_K2   = 10756096;      // 4*64*32     k2[kvh][c][d]
static constexpr size_t OFF_O    = 10764288;      // 4096*512
static constexpr size_t OFF_PACK = 12861440;      // 32768*4 (ulonglong2 per query)

#define LDB 132   // 128-tile GEMM LDS leading-dim pad
#define TILE_F (16 * LDB)

__device__ __forceinline__ float rdlane_f(float v, int lane) {
  return __int_as_float(__builtin_amdgcn_readlane(__float_as_int(v), lane));
}

__global__ __launch_bounds__(256) void freq_table_kernel(float* __restrict__ cosT,
    float* __restrict__ sinT) {
  int idx = blockIdx.x * 256 + threadIdx.x;   // 0..131071
  int s = idx >> 5;
  int dp = idx & 31;
  double e = (double)dp * (1.0 / 32.0);
  float pf = (float)pow(10000.0, e);
  float invf = 1.0f / pf;
  float argf = __fmul_rn((float)s, invf);
  cosT[idx] = (float)cos((double)argf);
  sinT[idx] = (float)sin((double)argf);
}

// QKV panel NT gemm, double-buffered LDS (one barrier per ktile).
// Direct Wq/Wk/Wv reads (block-uniform select). fmaf chain k-ascending
// within panel [z?384:0, z?512:384); C_z gets the partial.
__global__ __launch_bounds__(256) void gemm128_qkv(const float* __restrict__ A,
    const float* __restrict__ Wq, const float* __restrict__ Wk,
    const float* __restrict__ Wv, float* __restrict__ C1,
    float* __restrict__ C2) {
  __shared__ float As[2 * TILE_F];
  __shared__ float Bs[2 * TILE_F];
  const int tid = threadIdx.x;
  const int z = blockIdx.z;
  const int k0 = z ? 384 : 0;
  const int k1 = z ? 512 : 384;
  float* __restrict__ C = z ? C2 : C1;
  const int bm = blockIdx.y, bn = blockIdx.x;
  const int lrow = tid >> 1;          // 0..127
  const int lko = (tid & 1) << 3;     // 0 or 8
  const int ty = tid >> 4;
  const int tx = tid & 15;
  const float* Bbase = (bn < 4) ? (Wq + ((size_t)bn * 128) * 512)
                     : (bn < 6) ? (Wk + ((size_t)(bn - 4) * 128) * 512)
                                : (Wv + ((size_t)(bn - 6) * 128) * 512);
  const float* Ap = A + (size_t)(bm * 128 + lrow) * 512 + lko;
  const float* Bp = Bbase + (size_t)lrow * 512 + lko;
  float acc[8][8] = {{0.f}};
  float4 a0 = *(const float4*)(Ap + k0);
  float4 a1 = *(const float4*)(Ap + k0 + 4);
  float4 b0 = *(const float4*)(Bp + k0);
  float4 b1 = *(const float4*)(Bp + k0 + 4);
  int p = 0;
  for (int kt = k0; kt < k1; kt += 16) {
    float* Asp = As + p * TILE_F;
    float* Bsp = Bs + p * TILE_F;
    Asp[(lko + 0) * LDB + lrow] = a0.x;
    Asp[(lko + 1) * LDB + lrow] = a0.y;
    Asp[(lko + 2) * LDB + lrow] = a0.z;
    Asp[(lko + 3) * LDB + lrow] = a0.w;
    Asp[(lko + 4) * LDB + lrow] = a1.x;
    Asp[(lko + 5) * LDB + lrow] = a1.y;
    Asp[(lko + 6) * LDB + lrow] = a1.z;
    Asp[(lko + 7) * LDB + lrow] = a1.w;
    Bsp[(lko + 0) * LDB + lrow] = b0.x;
    Bsp[(lko + 1) * LDB + lrow] = b0.y;
    Bsp[(lko + 2) * LDB + lrow] = b0.z;
    Bsp[(lko + 3) * LDB + lrow] = b0.w;
    Bsp[(lko + 4) * LDB + lrow] = b1.x;
    Bsp[(lko + 5) * LDB + lrow] = b1.y;
    Bsp[(lko + 6) * LDB + lrow] = b1.z;
    Bsp[(lko + 7) * LDB + lrow] = b1.w;
    __syncthreads();
    if (kt + 16 < k1) {
      a0 = *(const float4*)(Ap + kt + 16);
      a1 = *(const float4*)(Ap + kt + 20);
      b0 = *(const float4*)(Bp + kt + 16);
      b1 = *(const float4*)(Bp + kt + 20);
    }
    #pragma unroll
    for (int k = 0; k < 16; ++k) {
      float4 al = *(const float4*)(&Asp[k * LDB + (ty << 2)]);
      float4 ah = *(const float4*)(&Asp[k * LDB + 64 + (ty << 2)]);
      float4 bl = *(const float4*)(&Bsp[k * LDB + (tx << 2)]);
      float4 bh = *(const float4*)(&Bsp[k * LDB + 64 + (tx << 2)]);
      float af[8] = {al.x, al.y, al.z, al.w, ah.x, ah.y, ah.z, ah.w};
      float bf[8] = {bl.x, bl.y, bl.z, bl.w, bh.x, bh.y, bh.z, bh.w};
      #pragma unroll
      for (int i2 = 0; i2 < 8; ++i2)
        #pragma unroll
        for (int j2 = 0; j2 < 8; ++j2)
          acc[i2][j2] = fmaf(af[i2], bf[j2], acc[i2][j2]);
    }
    p ^= 1;
  }
  #pragma unroll
  for (int i2 = 0; i2 < 8; ++i2) {
    int row = bm * 128 + ((i2 < 4) ? (ty << 2) + i2 : 64 + (ty << 2) + i2 - 4);
    float* Cp = C + (size_t)row * 1024 + bn * 128;
    *(float4*)(Cp + (tx << 2))      = make_float4(acc[i2][0], acc[i2][1], acc[i2][2], acc[i2][3]);
    *(float4*)(Cp + 64 + (tx << 2)) = make_float4(acc[i2][4], acc[i2][5], acc[i2][6], acc[i2][7]);
  }
}

// Out-projection NT gemm, 4-way split-k via grid-z, double-buffered LDS.
// Partial z covers k in [z*128, z*128+128); Cbase + z*(4096*N).
__global__ __launch_bounds__(256) void gemm128_out(const float* __restrict__ A,
    const float* __restrict__ B, float* __restrict__ Cbase, int N) {
  __shared__ float As[2 * TILE_F];
  __shared__ float Bs[2 * TILE_F];
  const int tid = threadIdx.x;
  const int z = blockIdx.z;
  const int k0 = z << 7;
  const int k1 = k0 + 128;
  float* __restrict__ C = Cbase + (size_t)z * ((size_t)4096 * N);
  const int bm = blockIdx.y, bn = blockIdx.x;
  const int lrow = tid >> 1;
  const int lko = (tid & 1) << 3;
  const int ty = tid >> 4;
  const int tx = tid & 15;
  const float* Ap = A + (size_t)(bm * 128 + lrow) * 512 + lko;
  const float* Bp = B + (size_t)(bn * 128 + lrow) * 512 + lko;
  float acc[8][8] = {{0.f}};
  float4 a0 = *(const float4*)(Ap + k0);
  float4 a1 = *(const float4*)(Ap + k0 + 4);
  float4 b0 = *(const float4*)(Bp + k0);
  float4 b1 = *(const float4*)(Bp + k0 + 4);
  int p = 0;
  for (int kt = k0; kt < k1; kt += 16) {
    float* Asp = As + p * TILE_F;
    float* Bsp = Bs + p * TILE_F;
    Asp[(lko + 0) * LDB + lrow] = a0.x;
    Asp[(lko + 1) * LDB + lrow] = a0.y;
    Asp[(lko + 2) * LDB + lrow] = a0.z;
    Asp[(lko + 3) * LDB + lrow] = a0.w;
    Asp[(lko + 4) * LDB + lrow] = a1.x;
    Asp[(lko + 5) * LDB + lrow] = a1.y;
    Asp[(lko + 6) * LDB + lrow] = a1.z;
    Asp[(lko + 7) * LDB + lrow] = a1.w;
    Bsp[(lko + 0) * LDB + lrow] = b0.x;
    Bsp[(lko + 1) * LDB + lrow] = b0.y;
    Bsp[(lko + 2) * LDB + lrow] = b0.z;
    Bsp[(lko + 3) * LDB + lrow] = b0.w;
    Bsp[(lko + 4) * LDB + lrow] = b1.x;
    Bsp[(lko + 5) * LDB + lrow] = b1.y;
    Bsp[(lko + 6) * LDB + lrow] = b1.z;
    Bsp[(lko + 7) * LDB + lrow] = b1.w;
    __syncthreads();
    if (kt + 16 < k1) {
      a0 = *(const float4*)(Ap + kt + 16);
      a1 = *(const float4*)(Ap + kt + 20);
      b0 = *(const float4*)(Bp + kt + 16);
      b1 = *(const float4*)(Bp + kt + 20);
    }
    #pragma unroll
    for (int k = 0; k < 16; ++k) {
      float4 al = *(const float4*)(&Asp[k * LDB + (ty << 2)]);
      float4 ah = *(const float4*)(&Asp[k * LDB + 64 + (ty << 2)]);
      float4 bl = *(const float4*)(&Bsp[k * LDB + (tx << 2)]);
      float4 bh = *(const float4*)(&Bsp[k * LDB + 64 + (tx << 2)]);
      float af[8] = {al.x, al.y, al.z, al.w, ah.x, ah.y, ah.z, ah.w};
      float bf[8] = {bl.x, bl.y, bl.z, bl.w, bh.x, bh.y, bh.z, bh.w};
      #pragma unroll
      for (int i2 = 0; i2 < 8; ++i2)
        #pragma unroll
        for (int j2 = 0; j2 < 8; ++j2)
          acc[i2][j2] = fmaf(af[i2], bf[j2], acc[i2][j2]);
    }
    p ^= 1;
  }
  #pragma unroll
  for (int i2 = 0; i2 < 8; ++i2) {
    int row = bm * 128 + ((i2 < 4) ? (ty << 2) + i2 : 64 + (ty << 2) + i2 - 4);
    float* Cp = C + (size_t)row * N + bn * 128;
    *(float4*)(Cp + (tx << 2))      = make_float4(acc[i2][0], acc[i2][1], acc[i2][2], acc[i2][3]);
    *(float4*)(Cp + 64 + (tx << 2)) = make_float4(acc[i2][4], acc[i2][5], acc[i2][6], acc[i2][7]);
  }
}

// d_out = fl32(fl32(fl32(o0+o1)+o2)+o3)   (value path)
__global__ __launch_bounds__(256) void combine4_kernel(const float* __restrict__ o0,
    const float* __restrict__ o1, const float* __restrict__ o2,
    const float* __restrict__ o3, float* __restrict__ out) {
  int i = blockIdx.x * 256 + threadIdx.x;
  out[i] = __fadd_rn(__fadd_rn(__fadd_rn(o0[i], o1[i]), o2[i]), o3[i]);
}

// k roped + v copied (q never materialized). One thread per (s, n-512).
__global__ __launch_bounds__(256) void kv_rope_kernel(const float* __restrict__ p1,
    const float* __restrict__ p2, const float* __restrict__ cosT,
    const float* __restrict__ sinT, float* __restrict__ kb,
    float* __restrict__ vb) {
  int id = blockIdx.x * 256 + threadIdx.x;    // 0 .. 4096*512-1
  int s = id >> 9;
  int n = 512 + (id & 511);
  int idx = (s << 10) + n;
  float val = __fadd_rn(p1[idx], p2[idx]);
  int d = n & 63;
  if (n < 768) {
    int pidx = idx ^ 32;                      // partner d^32 (bit5 of n)
    float pv = __fadd_rn(p1[pidx], p2[pidx]);
    float cs = cosT[(s << 5) + (d & 31)];
    float sn = sinT[(s << 5) + (d & 31)];
    float rot = (d < 32) ? -pv : pv;
    float out = __fadd_rn(__fmul_rn(val, cs), __fmul_rn(rot, sn));
    int kvh = (n - 512) >> 6;
    kb[((size_t)(kvh * 4096 + s) << 6) + d] = out;
  } else {
    int kvh = (n - 768) >> 6;
    vb[((size_t)(kvh * 4096 + s) << 6) + d] = val;
  }
}

__global__ __launch_bounds__(256) void k12_np_kernel(const float* __restrict__ kb,
    float* __restrict__ k1t, float* __restrict__ k2t) {
  int id = blockIdx.x * 256 + threadIdx.x;    // 0..16383
  int which = id >> 13;
  int rem = id & 8191;
  int kvh = rem >> 11;
  int rem2 = rem & 2047;
  int i = rem2 >> 5;
  int d = rem2 & 31;
  const float* base = kb + ((size_t)(kvh * 4096) << 6);
  if (which == 0) {
    float acc = base[((size_t)(i * 64) << 6) + d];
    for (int c = 1; c < 64; ++c)
      acc = __fadd_rn(acc, base[((size_t)(i * 64 + c) << 6) + d]);
    k1t[(kvh * 64 + i) * 32 + d] = acc;
  } else {
    float acc = base[((size_t)i << 6) + d + 32];
    for (int r = 1; r < 64; ++r)
      acc = __fadd_rn(acc, base[((size_t)(r * 64 + i) << 6) + d + 32]);
    k2t[(kvh * 64 + i) * 32 + d] = acc;
  }
}

// FUSED stage-1: rope q on load, compute 128x64 score tile (same fmaf chains
// over dp ascending) into LDS, bubble-scan columns -> packed top-8.
__global__ __launch_bounds__(256) void stage1_sel_kernel(
    const float* __restrict__ p1, const float* __restrict__ p2,
    const float* __restrict__ cosT, const float* __restrict__ sinT,
    const float* __restrict__ k1t, const float* __restrict__ k2t,
    unsigned long long* __restrict__ packs) {
  __shared__ float smem[8704];        // phase1: qs[0..4351], kd[4352..8575]
  float* qs = smem;                   // [d][s] stride 68
  float* kd = smem + 4352;            // [dp][r2] stride 132
  const int t = threadIdx.x;
  const int h = blockIdx.y;
  const int s0 = blockIdx.x * 64;
  const int kvh = h >> 1;
  #pragma unroll
  for (int i = 0; i < 16; ++i) {
    int j = t + i * 256;
    int ss = j >> 6, d = j & 63;
    int s = s0 + ss;
    int idx = (s << 10) + (h << 6) + d;
    float val = __fadd_rn(p1[idx], p2[idx]);
    float pv  = __fadd_rn(p1[idx ^ 32], p2[idx ^ 32]);
    float cs = cosT[(s << 5) + (d & 31)];
    float sn = sinT[(s << 5) + (d & 31)];
    float rot = (d < 32) ? -pv : pv;
    qs[d * 68 + ss] = __fadd_rn(__fmul_rn(val, cs), __fmul_rn(rot, sn));
  }
  #pragma unroll
  for (int i = 0; i < 8; ++i) {
    int j = t + i * 256;
    int r = j >> 5, d = j & 31;
    kd[d * 132 + r]      = k1t[(kvh * 64 + r) * 32 + d];
    kd[d * 132 + 64 + r] = k2t[(kvh * 64 + r) * 32 + d];
  }
  __syncthreads();
  const int ty = t >> 4;              // r-group
  const int tx = t & 15;              // s-group
  float acc1[4][4] = {{0.f}};
  float acc2[4][4] = {{0.f}};
  #pragma unroll
  for (int dp = 0; dp < 32; ++dp) {
    float4 kv1 = *(const float4*)&kd[dp * 132 + (ty << 2)];
    float4 kv2 = *(const float4*)&kd[dp * 132 + 64 + (ty << 2)];
    float4 q1 = *(const float4*)&qs[dp * 68 + (tx << 2)];
    float4 q2 = *(const float4*)&qs[(32 + dp) * 68 + (tx << 2)];
    float k1f[4] = {kv1.x, kv1.y, kv1.z, kv1.w};
    float k2f[4] = {kv2.x, kv2.y, kv2.z, kv2.w};
    float q1f[4] = {q1.x, q1.y, q1.z, q1.w};
    float q2f[4] = {q2.x, q2.y, q2.z, q2.w};
    #pragma unroll
    for (int i2 = 0; i2 < 4; ++i2)
      #pragma unroll
      for (int j2 = 0; j2 < 4; ++j2) {
        acc1[i2][j2] = fmaf(k1f[i2], q1f[j2], acc1[i2][j2]);
        acc2[i2][j2] = fmaf(k2f[i2], q2f[j2], acc2[i2][j2]);
      }
  }
  __syncthreads();
  float* sct = smem;                  // [r2][s] stride 68
  #pragma unroll
  for (int i2 = 0; i2 < 4; ++i2) {
    int r = (ty << 2) + i2;
    *(float4*)&sct[(size_t)r * 68 + (tx << 2)] =
        make_float4(acc1[i2][0], acc1[i2][1], acc1[i2][2], acc1[i2][3]);
    *(float4*)&sct[(size_t)(64 + r) * 68 + (tx << 2)] =
        make_float4(acc2[i2][0], acc2[i2][1], acc2[i2][2], acc2[i2][3]);
  }
  __syncthreads();
  if (t < 128) {
    int set = t >> 6;
    int sq = t & 63;
    const float* p = sct + (size_t)(set << 6) * 68 + sq;
    float top[8];
    int idx[8];
    #pragma unroll
    for (int u = 0; u < 8; ++u) { top[u] = -INFINITY; idx[u] = 0; }
    #pragma unroll
    for (int r = 0; r < 64; ++r) {
      float v = p[(size_t)r * 68];
      int i = r;
      #pragma unroll
      for (int j = 0; j < 8; ++j) {
        bool gt = v > top[j];
        float tv = top[j]; int ti = idx[j];
        top[j] = gt ? v : tv;
        idx[j] = gt ? i : ti;
        v = gt ? tv : v;
        i = gt ? ti : i;
      }
    }
    unsigned long long pp = 0;
    #pragma unroll
    for (int u = 0; u < 8; ++u) pp |= (unsigned long long)idx[u] << (6 * u);
    packs[(((size_t)(h * 4096 + s0 + sq)) << 1) + set] = pp;
  }
}

// Values-only bitonic sort (descending).
__device__ __forceinline__ void bitonic64_val_desc(float& v, int lane) {
  #pragma unroll
  for (int k = 2; k <= 64; k <<= 1) {
    #pragma unroll
    for (int j = k >> 1; j >= 1; j >>= 1) {
      float ov = __shfl_xor(v, j, 64);
      bool up = ((lane & k) == 0) == ((lane & j) == 0);
      float mx = fmaxf(v, ov), mn = fminf(v, ov);
      v = up ? mx : mn;
    }
  }
}

// Stage-2 + epilogue: one wave per query; rope q on load (shfl partner).
__global__ __launch_bounds__(256) void attn_sel2_kernel(
    const ulonglong2* __restrict__ packs, const float* __restrict__ p1,
    const float* __restrict__ p2, const float* __restrict__ cosT,
    const float* __restrict__ sinT, const float* __restrict__ vb,
    const float* __restrict__ k1t, const float* __restrict__ k2t,
    float* __restrict__ ob) {
  const int lane = threadIdx.x & 63;
  const int w = blockIdx.x * 4 + (threadIdx.x >> 6);   // w = h*4096 + s
  const int h = w >> 12;
  const int s = w & 4095;
  const int kvh = h >> 1;
  ulonglong2 pk = packs[w];
  const unsigned long long pack1 = pk.x, pack2 = pk.y;
  // rope q on load: lane = d
  int qidx = (s << 10) + (h << 6) + lane;
  float vraw = __fadd_rn(p1[qidx], p2[qidx]);
  float pv = __shfl_xor(vraw, 32, 64);
  float cs = cosT[(s << 5) + (lane & 31)];
  float sn = sinT[(s << 5) + (lane & 31)];
  float rot = (lane < 32) ? -pv : pv;
  const float qv = __fadd_rn(__fmul_rn(vraw, cs), __fmul_rn(rot, sn));

  int r1 = (int)((pack1 >> (6 * (lane >> 3))) & 63);
  int r2 = (int)((pack2 >> (6 * (lane & 7))) & 63);
  const float* k1p = k1t + (size_t)(kvh * 64 + r1) * 32;
  const float* k2p = k2t + (size_t)(kvh * 64 + r2) * 32;
  float c = 0.f;
  #pragma unroll
  for (int dq = 0; dq < 32; dq += 4) {
    float4 kk = *(const float4*)(k1p + dq);
    c = __fadd_rn(c, __fmul_rn(rdlane_f(qv, dq + 0), kk.x));
    c = __fadd_rn(c, __fmul_rn(rdlane_f(qv, dq + 1), kk.y));
    c = __fadd_rn(c, __fmul_rn(rdlane_f(qv, dq + 2), kk.z));
    c = __fadd_rn(c, __fmul_rn(rdlane_f(qv, dq + 3), kk.w));
  }
  #pragma unroll
  for (int dq = 0; dq < 32; dq += 4) {
    float4 kk = *(const float4*)(k2p + dq);
    c = __fadd_rn(c, __fmul_rn(rdlane_f(qv, 32 + dq + 0), kk.x));
    c = __fadd_rn(c, __fmul_rn(rdlane_f(qv, 32 + dq + 1), kk.y));
    c = __fadd_rn(c, __fmul_rn(rdlane_f(qv, 32 + dq + 2), kk.z));
    c = __fadd_rn(c, __fmul_rn(rdlane_f(qv, 32 + dq + 3), kk.w));
  }
  const float scand = c;
  float v3 = c;
  bitonic64_val_desc(v3, lane);
  float cvs[8]; int ccs[8];
  unsigned long long used = 0;
  #pragma unroll
  for (int t = 0; t < 8; ++t) {
    float tv = rdlane_f(v3, t);
    unsigned long long m = __ballot(scand == tv) & ~used;
    int ix = __ffsll((long long)m) - 1;
    used |= 1ull << ix;
    cvs[t] = tv;
    ccs[t] = ix;
  }
  float y[8];
  #pragma unroll
  for (int t = 0; t < 8; ++t) y[t] = cvs[t] * 0.125f;
  float mx = y[0];
  #pragma unroll
  for (int t = 1; t < 8; ++t) if (y[t] > mx) mx = y[t];
  float e[8];
  #pragma unroll
  for (int t = 0; t < 8; ++t) e[t] = __expf(__fsub_rn(y[t], mx));
  float wsum = __fadd_rn(__fadd_rn(__fadd_rn(e[0], e[1]), __fadd_rn(e[2], e[3])),
                         __fadd_rn(__fadd_rn(e[4], e[5]), __fadd_rn(e[6], e[7])));
  const float* vbh = vb + ((size_t)kvh << 18);
  float o = 0.f;
  #pragma unroll
  for (int t = 0; t < 8; ++t) {
    float att = __fdiv_rn(e[t], wsum);
    int row = (int)((pack1 >> (6 * (ccs[t] >> 3))) & 63);
    int col = (int)((pack2 >> (6 * (ccs[t] & 7))) & 63);
    o = __fadd_rn(o, __fmul_rn(att, vbh[((size_t)(row * 64 + col) << 6) + lane]));
  }
  ob[(size_t)s * 512 + (h << 6) + lane] = o;
}

extern "C" void kernel_launch(void* const* d_in, const int* in_sizes, int n_in,
                              void* d_out, int out_size, void* d_ws, size_t ws_size,
                              hipStream_t stream) {
  const float* x  = (const float*)d_in[0];
  const float* Wq = (const float*)d_in[1];
  const float* Wk = (const float*)d_in[2];
  const float* Wv = (const float*)d_in[3];
  const float* Wo = (const float*)d_in[4];
  float* ws = (float*)d_ws;
  float* p1   = ws + OFF_P1;
  float* p2   = ws + OFF_P2;
  float* kb   = ws + OFF_KB;
  float* vb   = ws + OFF_V;
  float* cosT = ws + OFF_COS;
  float* sinT = ws + OFF_SIN;
  float* k1t  = ws + OFF_K1;
  float* k2t  = ws + OFF_K2;
  float* ob   = ws + OFF_O;
  unsigned long long* packs = (unsigned long long*)(ws + OFF_PACK);
  // out partials overwrite p1/p2 regions (free after attn_sel2)
  float* op = ws + OFF_P1;            // 4 partials x 2M floats

  freq_table_kernel<<<512, 256, 0, stream>>>(cosT, sinT);
  gemm128_qkv<<<dim3(8, 32, 2), 256, 0, stream>>>(x, Wq, Wk, Wv, p1, p2);
  kv_rope_kernel<<<8192, 256, 0, stream>>>(p1, p2, cosT, sinT, kb, vb);
  k12_np_kernel<<<64, 256, 0, stream>>>(kb, k1t, k2t);
  stage1_sel_kernel<<<dim3(64, 8), 256, 0, stream>>>(p1, p2, cosT, sinT, k1t, k2t, packs);
  attn_sel2_kernel<<<8192, 256, 0, stream>>>((const ulonglong2*)packs, p1, p2,
                                             cosT, sinT, vb, k1t, k2t, ob);
  gemm128_out<<<dim3(4, 32, 4), 256, 0, stream>>>(ob, Wo, op, 512);
  combine4_kernel<<<8192, 256, 0, stream>>>(op, op + 2097152, op + 4194304,
                                            op + 6291456, (float*)d_out);
}